// Round 1
// baseline (653.027 us; speedup 1.0000x reference)
//
#include <hip/hip_runtime.h>

#define NNODES 50000
#define NEDGES 800000
#define NHEADS 4
#define HID 64
#define NEG_SLOPE 0.2f

// ---------------- graph prep ----------------

__global__ void init_kernel(int* deg, int* cursor) {
    int i = blockIdx.x * blockDim.x + threadIdx.x;
    if (i < NNODES) { deg[i] = 1; cursor[i] = 0; }  // deg starts at 1: self-loop
}

__global__ void hist_kernel(const int* dsts, int* deg) {
    int e = blockIdx.x * blockDim.x + threadIdx.x;
    if (e < NEDGES) atomicAdd(&deg[dsts[e]], 1);
}

// single-block exclusive scan over deg[0..N) -> rowstart[0..N]
__global__ void scan_kernel(const int* deg, int* rowstart) {
    const int n = NNODES;
    __shared__ int wsum[16];
    __shared__ int chunk_total;
    int t = threadIdx.x, lane = t & 63, wid = t >> 6;
    int carry = 0;
    for (int base = 0; base < n; base += 1024) {
        int i = base + t;
        int v = (i < n) ? deg[i] : 0;
        int incl = v;
#pragma unroll
        for (int off = 1; off < 64; off <<= 1) {
            int u = __shfl_up(incl, off, 64);
            if (lane >= off) incl += u;
        }
        if (lane == 63) wsum[wid] = incl;
        __syncthreads();
        if (t < 16) {
            int s = wsum[t];
            int si = s;
#pragma unroll
            for (int off = 1; off < 16; off <<= 1) {
                int u = __shfl_up(si, off, 64);
                if (t >= off) si += u;
            }
            wsum[t] = si - s;              // exclusive wave offset
            if (t == 15) chunk_total = si; // inclusive total of chunk
        }
        __syncthreads();
        if (i < n) rowstart[i] = carry + wsum[wid] + (incl - v);
        carry += chunk_total;
        __syncthreads();
    }
    if (t == 0) rowstart[n] = carry;
}

__global__ void scatter_kernel(const int* srcs, const int* dsts,
                               const int* rowstart, int* cursor, int* srclist) {
    int e = blockIdx.x * blockDim.x + threadIdx.x;
    if (e < NEDGES) {
        int s = srcs[e], d = dsts[e];
        int pos = atomicAdd(&cursor[d], 1);
        srclist[rowstart[d] + pos] = s;
    } else if (e < NEDGES + NNODES) {
        int d = e - NEDGES;
        int pos = atomicAdd(&cursor[d], 1);
        srclist[rowstart[d] + pos] = d;  // self-loop
    }
}

// ---------------- layer 1 ----------------

// one block (256 thr) per node: h1 = x @ W1, plus per-head attention dots
__global__ void layer1_proj(const float* __restrict__ x, const float* __restrict__ W1,
                            const float* __restrict__ att_src, const float* __restrict__ att_dst,
                            float* __restrict__ h1, float* __restrict__ asrc, float* __restrict__ adst) {
    int nid = blockIdx.x;
    int t = threadIdx.x;
    __shared__ float xr[16];
    if (t < 15) xr[t] = x[nid * 15 + t];
    __syncthreads();
    float acc = 0.f;
#pragma unroll
    for (int k = 0; k < 15; ++k) acc += xr[k] * W1[k * 256 + t];
    h1[nid * 256 + t] = acc;
    int h = t >> 6, d = t & 63;
    float ps = acc * att_src[h * 64 + d];
    float pd = acc * att_dst[h * 64 + d];
#pragma unroll
    for (int off = 32; off; off >>= 1) {
        ps += __shfl_down(ps, off, 64);
        pd += __shfl_down(pd, off, 64);
    }
    if (d == 0) { asrc[nid * NHEADS + h] = ps; adst[nid * NHEADS + h] = pd; }
}

// one block per dst node, one wave per head; segment softmax + weighted sum + bias + ELU
__global__ void layer1_aggr(const float* __restrict__ h1, const int* __restrict__ rowstart,
                            const int* __restrict__ srclist,
                            const float* __restrict__ asrc, const float* __restrict__ adst,
                            const float* __restrict__ b1, float* __restrict__ out1) {
    int nid = blockIdx.x;
    int t = threadIdx.x, h = t >> 6, lane = t & 63;
    int beg = rowstart[nid], end = rowstart[nid + 1];
    float ad = adst[nid * NHEADS + h];

    float m = -1e30f;
    for (int i = beg + lane; i < end; i += 64) {
        float e = asrc[srclist[i] * NHEADS + h] + ad;
        e = e > 0.f ? e : NEG_SLOPE * e;
        m = fmaxf(m, e);
    }
#pragma unroll
    for (int off = 32; off; off >>= 1) m = fmaxf(m, __shfl_down(m, off, 64));
    m = __shfl(m, 0, 64);

    float z = 0.f;
    for (int i = beg + lane; i < end; i += 64) {
        float e = asrc[srclist[i] * NHEADS + h] + ad;
        e = e > 0.f ? e : NEG_SLOPE * e;
        z += __expf(e - m);
    }
#pragma unroll
    for (int off = 32; off; off >>= 1) z += __shfl_down(z, off, 64);
    z = __shfl(z, 0, 64);

    float acc = 0.f;
    for (int i = beg; i < end; ++i) {
        int s = srclist[i];
        float e = asrc[s * NHEADS + h] + ad;
        e = e > 0.f ? e : NEG_SLOPE * e;
        float w = __expf(e - m);
        acc += w * h1[s * 256 + h * 64 + lane];
    }
    acc = acc / z + b1[h * 64 + lane];
    out1[nid * 256 + t] = acc > 0.f ? acc : __expf(acc) - 1.f;  // ELU
}

// ---------------- layer 2 ----------------

// one wave per node: h2 = elu_out @ W2 (256->64), plus attention dots (heads=1)
__global__ void layer2_proj(const float* __restrict__ out1, const float* __restrict__ W2,
                            const float* __restrict__ att_src2, const float* __restrict__ att_dst2,
                            float* __restrict__ h2, float* __restrict__ as2, float* __restrict__ ad2) {
    int nid = blockIdx.x;
    int t = threadIdx.x;  // 64
    __shared__ float row[256];
    for (int k = t; k < 256; k += 64) row[k] = out1[nid * 256 + k];
    __syncthreads();
    float acc = 0.f;
    for (int k = 0; k < 256; ++k) acc += row[k] * W2[k * 64 + t];
    h2[nid * 64 + t] = acc;
    float ps = acc * att_src2[t];
    float pd = acc * att_dst2[t];
#pragma unroll
    for (int off = 32; off; off >>= 1) {
        ps += __shfl_down(ps, off, 64);
        pd += __shfl_down(pd, off, 64);
    }
    if (t == 0) { as2[nid] = ps; ad2[nid] = pd; }
}

// one wave per dst node, head=1, D=64
__global__ void layer2_aggr(const float* __restrict__ h2, const int* __restrict__ rowstart,
                            const int* __restrict__ srclist,
                            const float* __restrict__ as2, const float* __restrict__ ad2,
                            const float* __restrict__ b2, float* __restrict__ out2) {
    int nid = blockIdx.x;
    int lane = threadIdx.x;
    int beg = rowstart[nid], end = rowstart[nid + 1];
    float ad = ad2[nid];

    float m = -1e30f;
    for (int i = beg + lane; i < end; i += 64) {
        float e = as2[srclist[i]] + ad;
        e = e > 0.f ? e : NEG_SLOPE * e;
        m = fmaxf(m, e);
    }
#pragma unroll
    for (int off = 32; off; off >>= 1) m = fmaxf(m, __shfl_down(m, off, 64));
    m = __shfl(m, 0, 64);

    float z = 0.f;
    for (int i = beg + lane; i < end; i += 64) {
        float e = as2[srclist[i]] + ad;
        e = e > 0.f ? e : NEG_SLOPE * e;
        z += __expf(e - m);
    }
#pragma unroll
    for (int off = 32; off; off >>= 1) z += __shfl_down(z, off, 64);
    z = __shfl(z, 0, 64);

    float acc = 0.f;
    for (int i = beg; i < end; ++i) {
        int s = srclist[i];
        float e = as2[s] + ad;
        e = e > 0.f ? e : NEG_SLOPE * e;
        acc += __expf(e - m) * h2[s * 64 + lane];
    }
    out2[nid * 64 + lane] = acc / z + b2[lane];
}

// ---------------- final mean over nodes ----------------

__global__ void reduce_kernel(const float* __restrict__ out2, float* __restrict__ dout) {
    int t = threadIdx.x;
    int col = t & 63, sub = t >> 6;
    float acc = 0.f;
    for (int r = blockIdx.x * 4 + sub; r < NNODES; r += 256 * 4)
        acc += out2[r * 64 + col];
    __shared__ float sh[256];
    sh[t] = acc;
    __syncthreads();
    if (t < 64) {
        float v = sh[t] + sh[t + 64] + sh[t + 128] + sh[t + 192];
        atomicAdd(&dout[t], v * (1.0f / NNODES));
    }
}

// ---------------- launch ----------------

extern "C" void kernel_launch(void* const* d_in, const int* in_sizes, int n_in,
                              void* d_out, int out_size, void* d_ws, size_t ws_size,
                              hipStream_t stream) {
    const float* x        = (const float*)d_in[0];
    const int*   ei       = (const int*)d_in[1];   // [2, E] -> src row then dst row
    const float* W1       = (const float*)d_in[2];
    const float* att_src1 = (const float*)d_in[3];
    const float* att_dst1 = (const float*)d_in[4];
    const float* b1       = (const float*)d_in[5];
    const float* W2       = (const float*)d_in[6];
    const float* att_src2 = (const float*)d_in[7];
    const float* att_dst2 = (const float*)d_in[8];
    const float* b2       = (const float*)d_in[9];
    float* out = (float*)d_out;

    char* ws = (char*)d_ws;
    size_t off = 0;
    auto take = [&](size_t bytes) -> char* {
        char* p = ws + off;
        off = (off + bytes + 255) & ~(size_t)255;
        return p;
    };
    int*   deg      = (int*)take(NNODES * sizeof(int));
    int*   rowstart = (int*)take((NNODES + 1) * sizeof(int));
    int*   cursor   = (int*)take(NNODES * sizeof(int));
    int*   srclist  = (int*)take((size_t)(NEDGES + NNODES) * sizeof(int));
    float* asrc1    = (float*)take((size_t)NNODES * NHEADS * sizeof(float));
    float* adst1    = (float*)take((size_t)NNODES * NHEADS * sizeof(float));
    float* h1       = (float*)take((size_t)NNODES * 256 * sizeof(float));
    float* out1     = (float*)take((size_t)NNODES * 256 * sizeof(float));
    // aliases: h1 is dead after layer1_aggr; asrc1/adst1 dead after layer1_aggr
    float* h2   = h1;
    float* out2 = h1 + (size_t)NNODES * 64;
    float* as2  = asrc1;
    float* ad2  = adst1;

    const int* srcs = ei;
    const int* dsts = ei + NEDGES;

    init_kernel<<<(NNODES + 255) / 256, 256, 0, stream>>>(deg, cursor);
    hist_kernel<<<(NEDGES + 255) / 256, 256, 0, stream>>>(dsts, deg);
    scan_kernel<<<1, 1024, 0, stream>>>(deg, rowstart);
    scatter_kernel<<<(NEDGES + NNODES + 255) / 256, 256, 0, stream>>>(srcs, dsts, rowstart, cursor, srclist);

    layer1_proj<<<NNODES, 256, 0, stream>>>(x, W1, att_src1, att_dst1, h1, asrc1, adst1);
    layer1_aggr<<<NNODES, 256, 0, stream>>>(h1, rowstart, srclist, asrc1, adst1, b1, out1);

    layer2_proj<<<NNODES, 64, 0, stream>>>(out1, W2, att_src2, att_dst2, h2, as2, ad2);
    layer2_aggr<<<NNODES, 64, 0, stream>>>(h2, rowstart, srclist, as2, ad2, b2, out2);

    hipMemsetAsync(d_out, 0, 64 * sizeof(float), stream);
    reduce_kernel<<<256, 256, 0, stream>>>(out2, out);
}

// Round 2
// 464.674 us; speedup vs baseline: 1.4053x; 1.4053x over previous
//
#include <hip/hip_runtime.h>
#include <hip/hip_fp16.h>

#define NNODES 50000
#define NEDGES 800000
#define NHEADS 4
#define HID 64
#define NEG_SLOPE 0.2f
#define NTOT (NEDGES + NNODES)

// ---------------- graph prep ----------------

__global__ void prep_init(int* deg, int* cursor) {
    int i = blockIdx.x * blockDim.x + threadIdx.x;
    if (i < NNODES) { deg[i] = 1; cursor[i] = 0; }  // deg starts at 1: self-loop
}

__global__ void hist_kernel(const int* __restrict__ dsts, int* __restrict__ deg) {
    int e = blockIdx.x * blockDim.x + threadIdx.x;
    if (e < NEDGES) atomicAdd(&deg[dsts[e]], 1);
}

// hierarchical exclusive scan: A (per-block), B (block totals), C (add offsets)
__global__ void scanA(const int* __restrict__ deg, int* __restrict__ rowstart,
                      int* __restrict__ partials) {
    int b = blockIdx.x, t = threadIdx.x, lane = t & 63, wid = t >> 6;
    int i = b * 256 + t;
    int v = (i < NNODES) ? deg[i] : 0;
    int incl = v;
#pragma unroll
    for (int off = 1; off < 64; off <<= 1) {
        int u = __shfl_up(incl, off, 64);
        if (lane >= off) incl += u;
    }
    __shared__ int ws[4];
    if (lane == 63) ws[wid] = incl;
    __syncthreads();
    int w0 = ws[0], w1 = ws[1], w2 = ws[2], w3 = ws[3];
    int woff = (wid > 0 ? w0 : 0) + (wid > 1 ? w1 : 0) + (wid > 2 ? w2 : 0);
    if (i < NNODES) rowstart[i] = woff + (incl - v);
    if (t == 0) partials[b] = w0 + w1 + w2 + w3;
}

__global__ void scanB(const int* __restrict__ partials, int* __restrict__ blockoff,
                      int* __restrict__ rowstart, int nb) {
    int t = threadIdx.x, lane = t & 63, wid = t >> 6;
    int v = (t < nb) ? partials[t] : 0;
    int incl = v;
#pragma unroll
    for (int off = 1; off < 64; off <<= 1) {
        int u = __shfl_up(incl, off, 64);
        if (lane >= off) incl += u;
    }
    __shared__ int ws[4];
    if (lane == 63) ws[wid] = incl;
    __syncthreads();
    int w0 = ws[0], w1 = ws[1], w2 = ws[2];
    int woff = (wid > 0 ? w0 : 0) + (wid > 1 ? w1 : 0) + (wid > 2 ? w2 : 0);
    if (t < nb) blockoff[t] = woff + (incl - v);
    if (t == 0) rowstart[NNODES] = NTOT;
}

__global__ void scanC(int* __restrict__ rowstart, const int* __restrict__ blockoff) {
    int b = blockIdx.x, t = threadIdx.x;
    int i = b * 256 + t;
    if (i < NNODES) rowstart[i] += blockoff[b];
}

__global__ void scatter_kernel(const int* __restrict__ srcs, const int* __restrict__ dsts,
                               const int* __restrict__ rowstart, int* __restrict__ cursor,
                               int* __restrict__ srclist) {
    int e = blockIdx.x * blockDim.x + threadIdx.x;
    if (e < NEDGES) {
        int s = srcs[e], d = dsts[e];
        int pos = atomicAdd(&cursor[d], 1);
        srclist[rowstart[d] + pos] = s;
    } else if (e < NTOT) {
        int d = e - NEDGES;
        int pos = atomicAdd(&cursor[d], 1);
        srclist[rowstart[d] + pos] = d;  // self-loop
    }
}

__global__ void w2_convert(const float* __restrict__ W2, __half* __restrict__ W2h) {
    int i = blockIdx.x * blockDim.x + threadIdx.x;
    if (i < 256 * 64) W2h[i] = __float2half(W2[i]);
}

// ---------------- layer 1 ----------------

// one block (256 thr) per node: h1 = x @ W1 (fp16 store), plus per-head attention dots
__global__ void layer1_proj(const float* __restrict__ x, const float* __restrict__ W1,
                            const float* __restrict__ att_src, const float* __restrict__ att_dst,
                            __half* __restrict__ h1, float* __restrict__ asrc,
                            float* __restrict__ adst) {
    int nid = blockIdx.x;
    int t = threadIdx.x;
    __shared__ float xr[16];
    if (t < 15) xr[t] = x[nid * 15 + t];
    __syncthreads();
    float acc = 0.f;
#pragma unroll
    for (int k = 0; k < 15; ++k) acc += xr[k] * W1[k * 256 + t];
    h1[nid * 256 + t] = __float2half(acc);
    int h = t >> 6, d = t & 63;
    float ps = acc * att_src[h * 64 + d];
    float pd = acc * att_dst[h * 64 + d];
#pragma unroll
    for (int off = 32; off; off >>= 1) {
        ps += __shfl_down(ps, off, 64);
        pd += __shfl_down(pd, off, 64);
    }
    if (d == 0) { asrc[nid * NHEADS + h] = ps; adst[nid * NHEADS + h] = pd; }
}

// one block per dst node, one wave per head; single-pass unnormalized softmax-aggregate.
// exp(e) without max-subtraction is exact for alpha = w/z (e is O(±5), no overflow risk).
__global__ void layer1_aggr(const __half* __restrict__ h1, const int* __restrict__ rowstart,
                            const int* __restrict__ srclist,
                            const float* __restrict__ asrc, const float* __restrict__ adst,
                            const float* __restrict__ b1, __half* __restrict__ out1) {
    int nid = blockIdx.x;
    int t = threadIdx.x, h = t >> 6, lane = t & 63;
    int sub = lane >> 5, d = lane & 31;  // sub: which edge of a pair; d: dim-pair index
    int beg = rowstart[nid], end = rowstart[nid + 1];
    float ad = adst[nid * NHEADS + h];

    float zl = 0.f, ax = 0.f, ay = 0.f;
    const __half2* hrow = (const __half2*)h1;
    for (int i0 = beg; i0 < end; i0 += 64) {
        int i = i0 + lane;
        int s = 0; float w = 0.f;
        if (i < end) {
            s = srclist[i];
            float e = asrc[s * NHEADS + h] + ad;
            e = fmaxf(e, NEG_SLOPE * e);  // LeakyReLU
            w = __expf(e);
        }
        zl += w;
        int cnt = end - i0; if (cnt > 64) cnt = 64;
        for (int j = 0; j < cnt; j += 2) {
            int jj = j + sub;                     // jj >= cnt reads lanes with w=0, s=0: harmless
            float wj = __shfl(w, jj, 64);
            int   sj = __shfl(s, jj, 64);
            float2 v = __half22float2(hrow[sj * 128 + h * 32 + d]);
            ax += wj * v.x;
            ay += wj * v.y;
        }
    }
#pragma unroll
    for (int off = 32; off; off >>= 1) zl += __shfl_xor(zl, off, 64);
    ax += __shfl_xor(ax, 32, 64);
    ay += __shfl_xor(ay, 32, 64);
    if (sub == 0) {
        float r = 1.f / zl;
        float2 bo = ((const float2*)b1)[h * 32 + d];
        float o0 = ax * r + bo.x;
        float o1 = ay * r + bo.y;
        o0 = o0 > 0.f ? o0 : __expf(o0) - 1.f;  // ELU
        o1 = o1 > 0.f ? o1 : __expf(o1) - 1.f;
        ((__half2*)out1)[nid * 128 + h * 32 + d] = __floats2half2_rn(o0, o1);
    }
}

// ---------------- layer 2 ----------------

// one wave per node: h2 = elu_out @ W2 (256->64, fp16 weights), plus attention dots (heads=1)
__global__ void layer2_proj(const __half* __restrict__ out1, const __half* __restrict__ W2h,
                            const float* __restrict__ att_src2, const float* __restrict__ att_dst2,
                            __half* __restrict__ h2, float* __restrict__ as2,
                            float* __restrict__ ad2) {
    int nid = blockIdx.x;
    int t = threadIdx.x;  // 64
    int sub = t >> 5, d = t & 31;
    __shared__ float row[256];
    const __half2* r = (const __half2*)(out1 + nid * 256);
    for (int k = t; k < 128; k += 64) {
        float2 v = __half22float2(r[k]);
        row[2 * k] = v.x; row[2 * k + 1] = v.y;
    }
    __syncthreads();
    float ax = 0.f, ay = 0.f;
    const __half2* wp = (const __half2*)W2h;  // [256][64] halves -> half2 index k*32+d
#pragma unroll 8
    for (int kk = 0; kk < 128; ++kk) {
        int k = sub * 128 + kk;
        float2 wv = __half22float2(wp[k * 32 + d]);
        float rv = row[k];
        ax += rv * wv.x;
        ay += rv * wv.y;
    }
    ax += __shfl_xor(ax, 32, 64);
    ay += __shfl_xor(ay, 32, 64);
    // both halves now hold full sums for dims (2d, 2d+1)
    if (sub == 0) ((__half2*)h2)[nid * 32 + d] = __floats2half2_rn(ax, ay);
    float2 asv = ((const float2*)att_src2)[d];
    float2 adv = ((const float2*)att_dst2)[d];
    float ps = ax * asv.x + ay * asv.y;
    float pd = ax * adv.x + ay * adv.y;
#pragma unroll
    for (int off = 16; off; off >>= 1) {
        ps += __shfl_xor(ps, off, 64);
        pd += __shfl_xor(pd, off, 64);
    }
    if (t == 0) { as2[nid] = ps; ad2[nid] = pd; }
}

// 4 waves per block, one node each; single-pass aggregate, D=64 (pair layout)
__global__ void layer2_aggr(const __half* __restrict__ h2, const int* __restrict__ rowstart,
                            const int* __restrict__ srclist,
                            const float* __restrict__ as2, const float* __restrict__ ad2,
                            const float* __restrict__ b2, float* __restrict__ out2) {
    int wid = threadIdx.x >> 6, lane = threadIdx.x & 63;
    int nid = blockIdx.x * 4 + wid;
    int sub = lane >> 5, d = lane & 31;
    int beg = rowstart[nid], end = rowstart[nid + 1];
    float ad = ad2[nid];

    float zl = 0.f, ax = 0.f, ay = 0.f;
    const __half2* hrow = (const __half2*)h2;
    for (int i0 = beg; i0 < end; i0 += 64) {
        int i = i0 + lane;
        int s = 0; float w = 0.f;
        if (i < end) {
            s = srclist[i];
            float e = as2[s] + ad;
            e = fmaxf(e, NEG_SLOPE * e);
            w = __expf(e);
        }
        zl += w;
        int cnt = end - i0; if (cnt > 64) cnt = 64;
        for (int j = 0; j < cnt; j += 2) {
            int jj = j + sub;
            float wj = __shfl(w, jj, 64);
            int   sj = __shfl(s, jj, 64);
            float2 v = __half22float2(hrow[sj * 32 + d]);
            ax += wj * v.x;
            ay += wj * v.y;
        }
    }
#pragma unroll
    for (int off = 32; off; off >>= 1) zl += __shfl_xor(zl, off, 64);
    ax += __shfl_xor(ax, 32, 64);
    ay += __shfl_xor(ay, 32, 64);
    if (sub == 0) {
        float r = 1.f / zl;
        float2 bo = ((const float2*)b2)[d];
        ((float2*)out2)[nid * 32 + d] = make_float2(ax * r + bo.x, ay * r + bo.y);
    }
}

// ---------------- final mean over nodes ----------------

__global__ void reduce_kernel(const float* __restrict__ out2, float* __restrict__ dout) {
    int t = threadIdx.x;
    int col = t & 63, sub = t >> 6;
    float acc = 0.f;
    for (int r = blockIdx.x * 4 + sub; r < NNODES; r += 256 * 4)
        acc += out2[r * 64 + col];
    __shared__ float sh[256];
    sh[t] = acc;
    __syncthreads();
    if (t < 64) {
        float v = sh[t] + sh[t + 64] + sh[t + 128] + sh[t + 192];
        atomicAdd(&dout[t], v * (1.0f / NNODES));
    }
}

// ---------------- launch ----------------

extern "C" void kernel_launch(void* const* d_in, const int* in_sizes, int n_in,
                              void* d_out, int out_size, void* d_ws, size_t ws_size,
                              hipStream_t stream) {
    const float* x        = (const float*)d_in[0];
    const int*   ei       = (const int*)d_in[1];   // [2, E] -> src row then dst row
    const float* W1       = (const float*)d_in[2];
    const float* att_src1 = (const float*)d_in[3];
    const float* att_dst1 = (const float*)d_in[4];
    const float* b1       = (const float*)d_in[5];
    const float* W2       = (const float*)d_in[6];
    const float* att_src2 = (const float*)d_in[7];
    const float* att_dst2 = (const float*)d_in[8];
    const float* b2       = (const float*)d_in[9];
    float* out = (float*)d_out;

    char* ws = (char*)d_ws;
    size_t off = 0;
    auto take = [&](size_t bytes) -> char* {
        char* p = ws + off;
        off = (off + bytes + 255) & ~(size_t)255;
        return p;
    };
    int*    deg      = (int*)take(NNODES * sizeof(int));
    int*    rowstart = (int*)take((NNODES + 1) * sizeof(int));
    int*    cursor   = (int*)take(NNODES * sizeof(int));
    int*    partials = (int*)take(256 * sizeof(int));
    int*    blockoff = (int*)take(256 * sizeof(int));
    int*    srclist  = (int*)take((size_t)NTOT * sizeof(int));
    float*  asrc1    = (float*)take((size_t)NNODES * NHEADS * sizeof(float));
    float*  adst1    = (float*)take((size_t)NNODES * NHEADS * sizeof(float));
    __half* h1       = (__half*)take((size_t)NNODES * 256 * sizeof(__half));
    __half* out1     = (__half*)take((size_t)NNODES * 256 * sizeof(__half));
    __half* h2       = (__half*)take((size_t)NNODES * 64 * sizeof(__half));
    float*  as2      = (float*)take((size_t)NNODES * sizeof(float));
    float*  ad2      = (float*)take((size_t)NNODES * sizeof(float));
    float*  out2     = (float*)take((size_t)NNODES * 64 * sizeof(float));
    __half* W2h      = (__half*)take(256 * 64 * sizeof(__half));

    const int* srcs = ei;
    const int* dsts = ei + NEDGES;
    const int NB = (NNODES + 255) / 256;  // 196

    prep_init<<<NB, 256, 0, stream>>>(deg, cursor);
    hist_kernel<<<(NEDGES + 255) / 256, 256, 0, stream>>>(dsts, deg);
    scanA<<<NB, 256, 0, stream>>>(deg, rowstart, partials);
    scanB<<<1, 256, 0, stream>>>(partials, blockoff, rowstart, NB);
    scanC<<<NB, 256, 0, stream>>>(rowstart, blockoff);
    scatter_kernel<<<(NTOT + 255) / 256, 256, 0, stream>>>(srcs, dsts, rowstart, cursor, srclist);
    w2_convert<<<64, 256, 0, stream>>>(W2, W2h);

    layer1_proj<<<NNODES, 256, 0, stream>>>(x, W1, att_src1, att_dst1, h1, asrc1, adst1);
    layer1_aggr<<<NNODES, 256, 0, stream>>>(h1, rowstart, srclist, asrc1, adst1, b1, out1);

    layer2_proj<<<NNODES, 64, 0, stream>>>(out1, W2h, att_src2, att_dst2, h2, as2, ad2);
    layer2_aggr<<<NNODES / 4, 256, 0, stream>>>(h2, rowstart, srclist, as2, ad2, b2, out2);

    hipMemsetAsync(d_out, 0, 64 * sizeof(float), stream);
    reduce_kernel<<<256, 256, 0, stream>>>(out2, out);
}